// Round 4
// baseline (304.118 us; speedup 1.0000x reference)
//
#include <hip/hip_runtime.h>
#include <cstdint>

using u16 = unsigned short;
using u32 = unsigned int;
typedef __attribute__((ext_vector_type(8))) short bf16x8;
typedef __attribute__((ext_vector_type(8))) u16 u16x8;
typedef __attribute__((ext_vector_type(16))) float f32x16;
typedef __attribute__((ext_vector_type(4))) float f32x4;
typedef __attribute__((ext_vector_type(4))) u16 u16x4;

#define DEV static __device__ __forceinline__

DEV u16 bf16_rne(float x) {
  u32 u = __float_as_uint(x);
  u32 r = (u + 0x7FFFu + ((u >> 16) & 1u)) >> 16;
  return (u16)r;
}
DEV float bf16f(u16 h) { return __uint_as_float(((u32)h) << 16); }

DEV float fast_tanh(float x) {
  float e = __expf(2.0f * x);
  return 1.0f - 2.0f / (e + 1.0f);
}
DEV float sigmoidf_(float x) { return 1.0f / (1.0f + __expf(-x)); }

// ---------------------------------------------------------------------------
// prep (merged): W_seq -> Wtb [P][D] bf16 transposed; GRU weights transposed.
// grid = D + 3H blocks of 256 threads.
// ---------------------------------------------------------------------------
__global__ void prep_all(const float* __restrict__ W,
                         const float* __restrict__ Wih,
                         const float* __restrict__ Whh, u16* __restrict__ Wtb,
                         float* __restrict__ WT, float* __restrict__ UT, int P,
                         int D, int G) {
  const int bid = blockIdx.x, tid = threadIdx.x;
  if (bid < D) {
    Wtb[(long)tid * D + bid] = bf16_rne(W[(long)bid * P + tid]);
  } else {
    const int g = bid - D;
    WT[(long)tid * G + g] = Wih[(long)g * D + tid];
    UT[(long)tid * G + g] = Whh[(long)g * D + tid];
  }
}

// ---------------------------------------------------------------------------
// GEMM: SP(bf16)[M][256] = bf16(A[M][256]) @ B[256][256], seqb = bf16(A).
// Barrier-free: 8 waves = 4 row-groups x 2 col-halves; wave = 32 rows x 128
// cols via mfma_f32_32x32x16_bf16 (acc 64 f32/lane). B-frags read directly
// from global (L2-hot, 128 KB total). A depth-1 reg prefetch. No LDS.
// ---------------------------------------------------------------------------
__global__ __launch_bounds__(512, 4) void gemm_sp(const float* __restrict__ A,
                                                  const u16* __restrict__ Bt,
                                                  u16* __restrict__ SP,
                                                  u16* __restrict__ seqb) {
  const int t = threadIdx.x;
  const int lane = t & 63;
  const int w = t >> 6;      // 0..7
  const int wrow = w >> 1;   // 0..3
  const int wcol = w & 1;    // 0..1
  const int l31 = lane & 31, koct = lane >> 5;
  const long rowb = (long)blockIdx.x * 128;
  const long row = rowb + wrow * 32 + l31;

  const float* arow_ = A + row * 256 + koct * 8;
  u16* srow = seqb + row * 256 + koct * 8;
  const u16* bbase = Bt + (long)(wcol * 128 + l31) * 256 + koct * 8;

  f32x16 acc[4];
#pragma unroll
  for (int i = 0; i < 4; ++i) acc[i] = (f32x16)0.f;

  float4 a_[2][2];
  a_[0][0] = *(const float4*)(arow_);
  a_[0][1] = *(const float4*)(arow_ + 4);

#pragma unroll 1
  for (int kt = 0; kt < 16; ++kt) {
    const int cur = kt & 1;
    if (kt < 15) {
      a_[cur ^ 1][0] = *(const float4*)(arow_ + (kt + 1) * 16);
      a_[cur ^ 1][1] = *(const float4*)(arow_ + (kt + 1) * 16 + 4);
    }
    u16x8 q;
#pragma unroll
    for (int e = 0; e < 4; ++e) {
      q[e] = bf16_rne(a_[cur][0][e]);
      q[4 + e] = bf16_rne(a_[cur][1][e]);
    }
    if ((kt >> 3) == wcol) *(u16x8*)(srow + kt * 16) = q;  // bf16 copy of A
    bf16x8 af = *(bf16x8*)&q;
#pragma unroll
    for (int fn = 0; fn < 4; ++fn) {
      bf16x8 bf = *(const bf16x8*)(bbase + (long)(fn * 32) * 256 + kt * 16);
      acc[fn] =
          __builtin_amdgcn_mfma_f32_32x32x16_bf16(af, bf, acc[fn], 0, 0, 0);
    }
  }

  // C/D 32x32 layout: col = lane&31, row = (reg&3) + 8*(reg>>2) + 4*(lane>>5)
#pragma unroll
  for (int fn = 0; fn < 4; ++fn) {
    const int col = wcol * 128 + fn * 32 + l31;
#pragma unroll
    for (int r = 0; r < 16; ++r) {
      const int rl = (r & 3) + 8 * (r >> 2) + 4 * koct;
      SP[(rowb + wrow * 32 + rl) * 256 + col] = bf16_rne(acc[fn][r]);
    }
  }
}

// ---------------------------------------------------------------------------
// Per-step fused kernel: hw = h@W_h (in-block), scores = v.tanh(SP+hw),
// e = exp(score) (max-free, |s|<=~11), block esum, vec partials from seqb.
// grid (NC, B), 256 threads.
// ---------------------------------------------------------------------------
__global__ __launch_bounds__(256) void step_scores_vec(
    const u16* __restrict__ SP, const u16* __restrict__ seqb,
    const float* __restrict__ hprev, const float* __restrict__ Wh,
    const float* __restrict__ v, const float* __restrict__ mask,
    float* __restrict__ wbuf, float* __restrict__ esum,
    float* __restrict__ part, int N, int B) {
  const int b = blockIdx.y, c = blockIdx.x, t = threadIdx.x;
  __shared__ float sh[256], shw[256], sv_[256], se[256];
  sh[t] = hprev[b * 256 + t];
  sv_[t] = v[t];
  __syncthreads();
  // hw[p=t] = sum_k h[k] * Wh[k][t]  (coalesced over t, Wh L2-hot)
  float hacc = 0.f;
#pragma unroll 4
  for (int k = 0; k < 256; ++k) hacc = fmaf(sh[k], Wh[(long)k * 256 + t], hacc);
  shw[t] = hacc;
  __syncthreads();

  const long rowg = (long)b * N + c * 256 + t;
  const bf16x8* rp = (const bf16x8*)(SP + rowg * 256);
  float s = 0.f;
#pragma unroll 8
  for (int j = 0; j < 32; ++j) {
    bf16x8 qv = rp[j];
#pragma unroll
    for (int e = 0; e < 8; ++e)
      s = fmaf(sv_[j * 8 + e], fast_tanh(bf16f((u16)qv[e]) + shw[j * 8 + e]),
               s);
  }
  float ev = (mask[rowg] > 0.f) ? __expf(s) : 0.f;
  se[t] = ev;
  wbuf[rowg] = ev;
  __syncthreads();
  if (t < 64) {
    float s4 = (se[t] + se[t + 64]) + (se[t + 128] + se[t + 192]);
#pragma unroll
    for (int off = 1; off < 64; off <<= 1) s4 += __shfl_xor(s4, off, 64);
    if (t == 0) esum[b * gridDim.x + c] = s4;
  }
  // vec partials: part[(c*4+isub)][b][d] = sum_{64 rows} e * seqb
  const int d4 = t & 63, isub = t >> 6;
  const u16* base = seqb + ((long)b * N + c * 256 + isub * 64) * 256 + d4 * 4;
  float a0 = 0, a1 = 0, a2 = 0, a3 = 0;
#pragma unroll 4
  for (int ii = 0; ii < 64; ++ii) {
    u16x4 qq = *(const u16x4*)(base + (long)ii * 256);
    float wv = se[isub * 64 + ii];
    a0 = fmaf(wv, bf16f(qq[0]), a0);
    a1 = fmaf(wv, bf16f(qq[1]), a1);
    a2 = fmaf(wv, bf16f(qq[2]), a2);
    a3 = fmaf(wv, bf16f(qq[3]), a3);
  }
  float4 res = {a0, a1, a2, a3};
  *(float4*)&part[((long)(c * 4 + isub) * B + b) * 256 + d4 * 4] = res;
}

// ---------------------------------------------------------------------------
// finalize: S-reduce, vec normalize, GRU (j-split over blockIdx.x),
// w-normalize + out write. grid (4, B).
// ---------------------------------------------------------------------------
__global__ __launch_bounds__(256) void finalize_gru(
    const float* __restrict__ part, const float* __restrict__ esumP, int ecnt,
    const float* __restrict__ hprev, const float* __restrict__ WT,
    const float* __restrict__ UT, const float* __restrict__ bih,
    const float* __restrict__ bhh, const float* __restrict__ wbuf,
    float* __restrict__ out, float* __restrict__ hnew, int N, int T, int step,
    int NP, int B) {
  const int q = blockIdx.x, b = blockIdx.y, t = threadIdx.x;
  __shared__ float sv[256], sh[256], sP[6][4][64];
  float S = 0.f;
  for (int i = 0; i < ecnt; ++i) S += esumP[b * ecnt + i];
  const float inv = 1.f / S;
  float a = 0.f;
  for (int cc = 0; cc < NP; ++cc) a += part[((long)cc * B + b) * 256 + t];
  sv[t] = a * inv;
  sh[t] = hprev[b * 256 + t];
  __syncthreads();
  const int j4 = t & 63, dg = t >> 6;
  const int j = q * 64 + j4;
  float g0 = 0, g1 = 0, g2 = 0, g3 = 0, g4 = 0, g5 = 0;
#pragma unroll 4
  for (int d = dg * 64; d < dg * 64 + 64; ++d) {
    const float vd = sv[d], hd = sh[d];
    const float* wr_ = WT + (long)d * 768 + j;
    const float* ur_ = UT + (long)d * 768 + j;
    g0 = fmaf(vd, wr_[0], g0);
    g1 = fmaf(vd, wr_[256], g1);
    g2 = fmaf(vd, wr_[512], g2);
    g3 = fmaf(hd, ur_[0], g3);
    g4 = fmaf(hd, ur_[256], g4);
    g5 = fmaf(hd, ur_[512], g5);
  }
  sP[0][dg][j4] = g0;
  sP[1][dg][j4] = g1;
  sP[2][dg][j4] = g2;
  sP[3][dg][j4] = g3;
  sP[4][dg][j4] = g4;
  sP[5][dg][j4] = g5;
  __syncthreads();
  if (t < 64) {
    const int jj = q * 64 + t;
    float xr = bih[jj], xz = bih[256 + jj], xn = bih[512 + jj];
    float hr = bhh[jj], hz = bhh[256 + jj], hn = bhh[512 + jj];
#pragma unroll
    for (int dgg = 0; dgg < 4; ++dgg) {
      xr += sP[0][dgg][t];
      xz += sP[1][dgg][t];
      xn += sP[2][dgg][t];
      hr += sP[3][dgg][t];
      hz += sP[4][dgg][t];
      hn += sP[5][dgg][t];
    }
    float rr = sigmoidf_(xr + hr);
    float zz = sigmoidf_(xz + hz);
    float nn = fast_tanh(xn + rr * hn);
    hnew[b * 256 + jj] = (1.f - zz) * nn + zz * sh[jj];
  }
  const long ob = ((long)b * T + step) * N;
  const int nq = N >> 2;
  for (int i = 0; i * 256 < nq; ++i) {
    const int n = q * nq + i * 256 + t;
    out[ob + n] = wbuf[(long)b * N + n] * inv;
  }
}

// ---------------------------------------------------------------------------
extern "C" void kernel_launch(void* const* d_in, const int* in_sizes, int n_in,
                              void* d_out, int out_size, void* d_ws,
                              size_t ws_size, hipStream_t stream) {
  (void)n_in;
  (void)ws_size;
  const float* seq = (const float*)d_in[0];
  const float* hidden = (const float*)d_in[1];
  const float* mask = (const float*)d_in[2];
  const float* Wseq = (const float*)d_in[4];
  const float* Wh = (const float*)d_in[5];
  const float* vatt = (const float*)d_in[6];
  const float* Wih = (const float*)d_in[7];
  const float* Whh = (const float*)d_in[8];
  const float* bih = (const float*)d_in[9];
  const float* bhh = (const float*)d_in[10];
  float* out = (float*)d_out;

  const int P = in_sizes[6];
  const int D = in_sizes[4] / P;
  const int H = in_sizes[5] / P;
  const int B = in_sizes[1] / H;
  const int N = in_sizes[2] / B;
  const int T = out_size / (B * N);
  const long M = (long)B * N;
  const int NC = N / 256;

  char* p = (char*)d_ws;
  auto alloc = [&](size_t bytes) {
    char* r = p;
    p += (bytes + 255) & ~(size_t)255;
    return r;
  };
  u16* SP = (u16*)alloc((size_t)M * P * 2);
  u16* seqb = (u16*)alloc((size_t)M * D * 2);
  u16* Wtb = (u16*)alloc((size_t)P * D * 2);
  float* WihT = (float*)alloc((size_t)D * 3 * H * 4);
  float* WhhT = (float*)alloc((size_t)H * 3 * H * 4);
  float* wbuf = (float*)alloc((size_t)B * N * 4);
  float* hA = (float*)alloc((size_t)B * H * 4);
  float* hB = (float*)alloc((size_t)B * H * 4);
  float* part = (float*)alloc((size_t)NC * 4 * B * 256 * 4);
  float* esum = (float*)alloc((size_t)B * NC * 4);
  float* hbuf[2] = {hA, hB};

  prep_all<<<dim3(D + 3 * H), dim3(256), 0, stream>>>(Wseq, Wih, Whh, Wtb,
                                                      WihT, WhhT, P, D, 3 * H);
  gemm_sp<<<dim3((int)(M / 128)), dim3(512), 0, stream>>>(seq, Wtb, SP, seqb);

  for (int t = 0; t < T; ++t) {
    const float* hcur = (t == 0) ? hidden : hbuf[(t - 1) & 1];
    step_scores_vec<<<dim3(NC, B), dim3(256), 0, stream>>>(
        SP, seqb, hcur, Wh, vatt, mask, wbuf, esum, part, N, B);
    finalize_gru<<<dim3(4, B), dim3(256), 0, stream>>>(
        part, esum, NC, hcur, WihT, WhhT, bih, bhh, wbuf, out, hbuf[t & 1], N,
        T, t, NC * 4, B);
  }
}

// Round 5
// 277.590 us; speedup vs baseline: 1.0956x; 1.0956x over previous
//
#include <hip/hip_runtime.h>
#include <cstdint>

using u16 = unsigned short;
using u32 = unsigned int;
typedef __attribute__((ext_vector_type(8))) short bf16x8;
typedef __attribute__((ext_vector_type(8))) u16 u16x8;
typedef __attribute__((ext_vector_type(16))) float f32x16;
typedef __attribute__((ext_vector_type(4))) u16 u16x4;
typedef __attribute__((ext_vector_type(4))) u32 u32x4;

#define DEV static __device__ __forceinline__

DEV float bf16f(u16 h) { return __uint_as_float(((u32)h) << 16); }

// packed f32x2 -> bf16x2 (RNE). lo -> bits[15:0], hi -> bits[31:16].
DEV u32 cvt_pk_bf16(float lo, float hi) {
  u32 d;
  asm("v_cvt_pk_bf16_f32 %0, %1, %2" : "=v"(d) : "v"(lo), "v"(hi));
  return d;
}

DEV float fast_tanh(float x) {
  float e = __expf(2.0f * x);
  return 1.0f - 2.0f / (e + 1.0f);
}
DEV float sigmoidf_(float x) { return 1.0f / (1.0f + __expf(-x)); }

// ---------------------------------------------------------------------------
// prep: [0, SB) blocks: seqb = bf16(seq) (2048 elems/block);
//       [SB, SB+D): Wtb[p][k] = bf16(W_seq[k][p]);
//       [SB+D, SB+D+3H): GRU weight transposes.
// ---------------------------------------------------------------------------
__global__ __launch_bounds__(256) void prep_all(
    const float* __restrict__ seq, const float* __restrict__ W,
    const float* __restrict__ Wih, const float* __restrict__ Whh,
    u16* __restrict__ seqb, u16* __restrict__ Wtb, float* __restrict__ WT,
    float* __restrict__ UT, int SB, int P, int D, int G) {
  const int bid = blockIdx.x, t = threadIdx.x;
  if (bid < SB) {
    const long i = (long)bid * 2048 + t * 8;
    float4 a = *(const float4*)(seq + i);
    float4 c = *(const float4*)(seq + i + 4);
    u32x4 o;
    o[0] = cvt_pk_bf16(a.x, a.y);
    o[1] = cvt_pk_bf16(a.z, a.w);
    o[2] = cvt_pk_bf16(c.x, c.y);
    o[3] = cvt_pk_bf16(c.z, c.w);
    *(u32x4*)(seqb + i) = o;
  } else if (bid < SB + D) {
    const int k = bid - SB;
    u32 pk = cvt_pk_bf16(W[(long)k * P + t], 0.f);
    Wtb[(long)t * D + k] = (u16)(pk & 0xFFFF);
  } else {
    const int g = bid - SB - D;
    WT[(long)t * G + g] = Wih[(long)g * D + t];
    UT[(long)t * G + g] = Whh[(long)g * D + t];
  }
}

// ---------------------------------------------------------------------------
// hw[b][p] = sum_k h[b][k] * W_h[k][p]
// ---------------------------------------------------------------------------
__global__ __launch_bounds__(256) void hw_kernel(const float* __restrict__ h,
                                                 const float* __restrict__ Wh,
                                                 float* __restrict__ hw) {
  const int b = blockIdx.x, pp = threadIdx.x;
  __shared__ float sh[256];
  sh[pp] = h[b * 256 + pp];
  __syncthreads();
  float acc = 0.f;
#pragma unroll 4
  for (int k = 0; k < 256; ++k) acc = fmaf(sh[k], Wh[(long)k * 256 + pp], acc);
  hw[b * 256 + pp] = acc;
}

// ---------------------------------------------------------------------------
// bigstep: per (b, 256-row chunk): recompute seq_proj via MFMA (Wtb staged
// once in LDS, barrier-free K-loop), fused scores/exp/esum + vec partials.
// 1024 thr = 16 waves = 4 rowgroups(64) x 4 colgroups(64); wave acc 64 f32.
// ---------------------------------------------------------------------------
__global__ __launch_bounds__(1024, 4) void bigstep(
    const u16* __restrict__ seqb, const u16* __restrict__ Wtb,
    const float* __restrict__ hwbuf, const float* __restrict__ vatt,
    const float* __restrict__ mask, float* __restrict__ wbuf,
    float* __restrict__ esum, float* __restrict__ part, int N, int B) {
  __shared__ u16 sB[32][256][8];  // 128 KB: [k-plane(8)][col][elem]
  __shared__ float sQ[256][4];
  __shared__ float se[256], shw[256], svv[256], sredE[4];

  const int t = threadIdx.x;
  const int lane = t & 63;
  const int w = t >> 6;        // 0..15
  const int wrg = w >> 2;      // row group (64 rows)
  const int wcg = w & 3;       // col group (64 cols)
  const int l31 = lane & 31, koct = lane >> 5;
  const int b = blockIdx.y, chunk = blockIdx.x;
  const int nchunks = gridDim.x;

  // stage B: thread t covers col=t&255, planes (t>>8)*8 .. +8
  {
    const int col = t & 255, p0 = (t >> 8) * 8;
    const u16* src = Wtb + (long)col * 256 + p0 * 8;
#pragma unroll
    for (int i = 0; i < 8; ++i)
      *(u16x8*)&sB[p0 + i][col][0] = *(const u16x8*)(src + i * 8);
  }
  if (t < 256) {
    shw[t] = hwbuf[b * 256 + t];
    svv[t] = vatt[t];
  }
  __syncthreads();

  // K-loop: A direct-to-reg (named double-buffer), B from LDS, no barriers.
  const long rowbase = (long)b * N + chunk * 256;
  const u16* ap0 = seqb + (rowbase + wrg * 64 + l31) * 256 + koct * 8;
  const u16* ap1 = ap0 + 32 * 256;

  f32x16 acc00 = (f32x16)0.f, acc01 = (f32x16)0.f;
  f32x16 acc10 = (f32x16)0.f, acc11 = (f32x16)0.f;

  u16x8 a0A = *(const u16x8*)(ap0);
  u16x8 a1A = *(const u16x8*)(ap1);
  u16x8 a0B, a1B;

#pragma unroll 1
  for (int kt2 = 0; kt2 < 8; ++kt2) {
    const int ktA = kt2 * 2, ktB = ktA + 1;
    // prefetch ktB
    a0B = *(const u16x8*)(ap0 + ktB * 16);
    a1B = *(const u16x8*)(ap1 + ktB * 16);
    {
      bf16x8 bf0 = *(bf16x8*)&sB[ktA * 2 + koct][wcg * 64 + l31][0];
      bf16x8 bf1 = *(bf16x8*)&sB[ktA * 2 + koct][wcg * 64 + 32 + l31][0];
      bf16x8 af0 = *(bf16x8*)&a0A, af1 = *(bf16x8*)&a1A;
      acc00 = __builtin_amdgcn_mfma_f32_32x32x16_bf16(af0, bf0, acc00, 0, 0, 0);
      acc01 = __builtin_amdgcn_mfma_f32_32x32x16_bf16(af0, bf1, acc01, 0, 0, 0);
      acc10 = __builtin_amdgcn_mfma_f32_32x32x16_bf16(af1, bf0, acc10, 0, 0, 0);
      acc11 = __builtin_amdgcn_mfma_f32_32x32x16_bf16(af1, bf1, acc11, 0, 0, 0);
    }
    // prefetch ktA+2
    if (kt2 < 7) {
      a0A = *(const u16x8*)(ap0 + (ktA + 2) * 16);
      a1A = *(const u16x8*)(ap1 + (ktA + 2) * 16);
    }
    {
      bf16x8 bf0 = *(bf16x8*)&sB[ktB * 2 + koct][wcg * 64 + l31][0];
      bf16x8 bf1 = *(bf16x8*)&sB[ktB * 2 + koct][wcg * 64 + 32 + l31][0];
      bf16x8 af0 = *(bf16x8*)&a0B, af1 = *(bf16x8*)&a1B;
      acc00 = __builtin_amdgcn_mfma_f32_32x32x16_bf16(af0, bf0, acc00, 0, 0, 0);
      acc01 = __builtin_amdgcn_mfma_f32_32x32x16_bf16(af0, bf1, acc01, 0, 0, 0);
      acc10 = __builtin_amdgcn_mfma_f32_32x32x16_bf16(af1, bf0, acc10, 0, 0, 0);
      acc11 = __builtin_amdgcn_mfma_f32_32x32x16_bf16(af1, bf1, acc11, 0, 0, 0);
    }
  }

  // epilogue: scores. col0 = wcg*64+l31, col1 = +32.
  const float vf0 = svv[wcg * 64 + l31], vf1 = svv[wcg * 64 + 32 + l31];
  const float hf0 = shw[wcg * 64 + l31], hf1 = shw[wcg * 64 + 32 + l31];
  float p0[16], p1[16];
#pragma unroll
  for (int r = 0; r < 16; ++r) {
    p0[r] = fmaf(vf0, fast_tanh(acc00[r] + hf0),
                 vf1 * fast_tanh(acc01[r] + hf1));
    p1[r] = fmaf(vf0, fast_tanh(acc10[r] + hf0),
                 vf1 * fast_tanh(acc11[r] + hf1));
  }
#pragma unroll
  for (int off = 1; off < 32; off <<= 1)
#pragma unroll
    for (int r = 0; r < 16; ++r) {
      p0[r] += __shfl_xor(p0[r], off, 32);
      p1[r] += __shfl_xor(p1[r], off, 32);
    }
  if (l31 == 0) {
#pragma unroll
    for (int r = 0; r < 16; ++r) {
      const int rl = (r & 3) + 8 * (r >> 2) + 4 * koct;
      sQ[wrg * 64 + rl][wcg] = p0[r];
      sQ[wrg * 64 + 32 + rl][wcg] = p1[r];
    }
  }
  __syncthreads();

  if (t < 256) {
    float s = (sQ[t][0] + sQ[t][1]) + (sQ[t][2] + sQ[t][3]);
    const long n = rowbase + t;
    float e = (mask[n] > 0.f) ? __expf(s) : 0.f;
    se[t] = e;
    wbuf[n] = e;
    float s4 = e;
#pragma unroll
    for (int off = 1; off < 64; off <<= 1) s4 += __shfl_xor(s4, off, 64);
    if (lane == 0) sredE[t >> 6] = s4;
  }
  __syncthreads();
  if (t == 0)
    esum[b * nchunks + chunk] =
        (sredE[0] + sredE[1]) + (sredE[2] + sredE[3]);

  // vec partials: rg = t>>6 (16 groups x 16 rows), d4 = t&63 (4 d's)
  const int d4 = t & 63, rg = t >> 6;
  const u16* base = seqb + (rowbase + rg * 16) * 256 + d4 * 4;
  float a0 = 0, a1 = 0, a2 = 0, a3 = 0;
#pragma unroll
  for (int ii = 0; ii < 16; ++ii) {
    u16x4 q = *(const u16x4*)(base + (long)ii * 256);
    float wv = se[rg * 16 + ii];
    a0 = fmaf(wv, bf16f(q[0]), a0);
    a1 = fmaf(wv, bf16f(q[1]), a1);
    a2 = fmaf(wv, bf16f(q[2]), a2);
    a3 = fmaf(wv, bf16f(q[3]), a3);
  }
  float4 res = {a0, a1, a2, a3};
  *(float4*)&part[((long)(chunk * 16 + rg) * B + b) * 256 + d4 * 4] = res;
}

// ---------------------------------------------------------------------------
// finalize: S-reduce, vec normalize, GRU (j-split over blockIdx.x),
// w-normalize + out write. grid (4, B).
// ---------------------------------------------------------------------------
__global__ __launch_bounds__(256) void finalize_gru(
    const float* __restrict__ part, const float* __restrict__ esumP, int ecnt,
    const float* __restrict__ hprev, const float* __restrict__ WT,
    const float* __restrict__ UT, const float* __restrict__ bih,
    const float* __restrict__ bhh, const float* __restrict__ wbuf,
    float* __restrict__ out, float* __restrict__ hnew, int N, int T, int step,
    int NP, int B) {
  const int q = blockIdx.x, b = blockIdx.y, t = threadIdx.x;
  __shared__ float sv[256], sh[256], sP[6][4][64];
  float S = 0.f;
  for (int i = 0; i < ecnt; ++i) S += esumP[b * ecnt + i];
  const float inv = 1.f / S;
  float a = 0.f;
  for (int cc = 0; cc < NP; ++cc) a += part[((long)cc * B + b) * 256 + t];
  sv[t] = a * inv;
  sh[t] = hprev[b * 256 + t];
  __syncthreads();
  const int j4 = t & 63, dg = t >> 6;
  const int j = q * 64 + j4;
  float g0 = 0, g1 = 0, g2 = 0, g3 = 0, g4 = 0, g5 = 0;
#pragma unroll 4
  for (int d = dg * 64; d < dg * 64 + 64; ++d) {
    const float vd = sv[d], hd = sh[d];
    const float* wr_ = WT + (long)d * 768 + j;
    const float* ur_ = UT + (long)d * 768 + j;
    g0 = fmaf(vd, wr_[0], g0);
    g1 = fmaf(vd, wr_[256], g1);
    g2 = fmaf(vd, wr_[512], g2);
    g3 = fmaf(hd, ur_[0], g3);
    g4 = fmaf(hd, ur_[256], g4);
    g5 = fmaf(hd, ur_[512], g5);
  }
  sP[0][dg][j4] = g0;
  sP[1][dg][j4] = g1;
  sP[2][dg][j4] = g2;
  sP[3][dg][j4] = g3;
  sP[4][dg][j4] = g4;
  sP[5][dg][j4] = g5;
  __syncthreads();
  if (t < 64) {
    const int jj = q * 64 + t;
    float xr = bih[jj], xz = bih[256 + jj], xn = bih[512 + jj];
    float hr = bhh[jj], hz = bhh[256 + jj], hn = bhh[512 + jj];
#pragma unroll
    for (int dgg = 0; dgg < 4; ++dgg) {
      xr += sP[0][dgg][t];
      xz += sP[1][dgg][t];
      xn += sP[2][dgg][t];
      hr += sP[3][dgg][t];
      hz += sP[4][dgg][t];
      hn += sP[5][dgg][t];
    }
    float rr = sigmoidf_(xr + hr);
    float zz = sigmoidf_(xz + hz);
    float nn = fast_tanh(xn + rr * hn);
    hnew[b * 256 + jj] = (1.f - zz) * nn + zz * sh[jj];
  }
  const long ob = ((long)b * T + step) * N;
  const int nq = N >> 2;
  for (int i = 0; i * 256 < nq; ++i) {
    const int n = q * nq + i * 256 + t;
    out[ob + n] = wbuf[(long)b * N + n] * inv;
  }
}

// ---------------------------------------------------------------------------
extern "C" void kernel_launch(void* const* d_in, const int* in_sizes, int n_in,
                              void* d_out, int out_size, void* d_ws,
                              size_t ws_size, hipStream_t stream) {
  (void)n_in;
  (void)ws_size;
  const float* seq = (const float*)d_in[0];
  const float* hidden = (const float*)d_in[1];
  const float* mask = (const float*)d_in[2];
  const float* Wseq = (const float*)d_in[4];
  const float* Wh = (const float*)d_in[5];
  const float* vatt = (const float*)d_in[6];
  const float* Wih = (const float*)d_in[7];
  const float* Whh = (const float*)d_in[8];
  const float* bih = (const float*)d_in[9];
  const float* bhh = (const float*)d_in[10];
  float* out = (float*)d_out;

  const int P = in_sizes[6];
  const int D = in_sizes[4] / P;
  const int H = in_sizes[5] / P;
  const int B = in_sizes[1] / H;
  const int N = in_sizes[2] / B;
  const int T = out_size / (B * N);
  const long M = (long)B * N;
  const int nchunks = N / 256;
  const int NP = nchunks * 16;
  const int SB = (int)(M * D / 2048);

  char* p = (char*)d_ws;
  auto alloc = [&](size_t bytes) {
    char* r = p;
    p += (bytes + 255) & ~(size_t)255;
    return r;
  };
  u16* seqb = (u16*)alloc((size_t)M * D * 2);
  u16* Wtb = (u16*)alloc((size_t)P * D * 2);
  float* WihT = (float*)alloc((size_t)D * 3 * H * 4);
  float* WhhT = (float*)alloc((size_t)H * 3 * H * 4);
  float* wbuf = (float*)alloc((size_t)B * N * 4);
  float* hwbuf = (float*)alloc((size_t)B * P * 4);
  float* hA = (float*)alloc((size_t)B * H * 4);
  float* hB = (float*)alloc((size_t)B * H * 4);
  float* part = (float*)alloc((size_t)NP * B * 256 * 4);
  float* esum = (float*)alloc((size_t)B * nchunks * 4);
  float* hbuf[2] = {hA, hB};

  prep_all<<<dim3(SB + D + 3 * H), dim3(256), 0, stream>>>(
      seq, Wseq, Wih, Whh, seqb, Wtb, WihT, WhhT, SB, P, D, 3 * H);

  for (int t = 0; t < T; ++t) {
    const float* hcur = (t == 0) ? hidden : hbuf[(t - 1) & 1];
    hw_kernel<<<dim3(B), dim3(256), 0, stream>>>(hcur, Wh, hwbuf);
    bigstep<<<dim3(nchunks, B), dim3(1024), 0, stream>>>(
        seqb, Wtb, hwbuf, vatt, mask, wbuf, esum, part, N, B);
    finalize_gru<<<dim3(4, B), dim3(256), 0, stream>>>(
        part, esum, nchunks, hcur, WihT, WhhT, bih, bhh, wbuf, out,
        hbuf[t & 1], N, T, t, NP, B);
  }
}

// Round 7
// 161.735 us; speedup vs baseline: 1.8804x; 1.7163x over previous
//
#include <hip/hip_runtime.h>
#include <cstdint>

using u16 = unsigned short;
using u32 = unsigned int;
typedef __attribute__((ext_vector_type(8))) short bf16x8;
typedef __attribute__((ext_vector_type(8))) u16 u16x8;
typedef __attribute__((ext_vector_type(16))) float f32x16;
typedef __attribute__((ext_vector_type(4))) u16 u16x4;
typedef __attribute__((ext_vector_type(4))) u32 u32x4;

#define DEV static __device__ __forceinline__

DEV u16 bf16_rne(float x) {
  u32 u = __float_as_uint(x);
  u32 r = (u + 0x7FFFu + ((u >> 16) & 1u)) >> 16;
  return (u16)r;
}
DEV float bf16f(u16 h) { return __uint_as_float(((u32)h) << 16); }

DEV u32 cvt_pk_bf16(float lo, float hi) {
  u32 d;
  asm("v_cvt_pk_bf16_f32 %0, %1, %2" : "=v"(d) : "v"(lo), "v"(hi));
  return d;
}

DEV float fast_tanh(float x) {
  float e = __expf(2.0f * x);
  return 1.0f - 2.0f / (e + 1.0f);
}
DEV float sigmoidf_(float x) { return 1.0f / (1.0f + __expf(-x)); }

// ---------------------------------------------------------------------------
// prep_seqF: seq f32 [b][n][d] -> seqF bf16 in MFMA-fragment order.
// Fragment unit (t8,kt) at elem offset (t8*16+kt)*512; within it lane l
// holds 8 elems: row n = t8*32 + (l&31), d = kt*16 + (l>>5)*8 + e.
// Via LDS transpose (XOR-swizzled), coalesced global read AND write.
// ---------------------------------------------------------------------------
__global__ __launch_bounds__(1024) void prep_seqF(const float* __restrict__ seq,
                                                  u16* __restrict__ seqF,
                                                  int N, int NCH) {
  __shared__ u16 sR[65536];  // 128 KB
  const int b = blockIdx.y, chunk = blockIdx.x, t = threadIdx.x;
  const float* src = seq + ((long)b * N + chunk * 256) * 256;
  char* sRb = (char*)sR;
#pragma unroll
  for (int i = 0; i < 8; ++i) {
    const int idx = i * 8192 + t * 8;
    float4 x = *(const float4*)(src + idx);
    float4 y = *(const float4*)(src + idx + 4);
    u32x4 o;
    o[0] = cvt_pk_bf16(x.x, x.y);
    o[1] = cvt_pk_bf16(x.z, x.w);
    o[2] = cvt_pk_bf16(y.x, y.y);
    o[3] = cvt_pk_bf16(y.z, y.w);
    const int row = idx >> 8;
    const int colb = (idx & 255) * 2;
    *(u32x4*)(sRb + row * 512 + (colb ^ ((row & 31) << 4))) = o;
  }
  __syncthreads();
  u16* dst = seqF + ((long)(b * NCH + chunk) << 16);
#pragma unroll
  for (int i = 0; i < 8; ++i) {
    const int u = i * 1024 + t;
    const int lane = u & 63, kt = (u >> 6) & 15, t8 = u >> 10;
    const int row = t8 * 32 + (lane & 31);
    const int colb = (kt * 16 + (lane >> 5) * 8) * 2;
    u16x8 v = *(const u16x8*)(sRb + row * 512 + (colb ^ ((row & 31) << 4)));
    *(u16x8*)(dst + (long)u * 8) = v;
  }
}

// ---------------------------------------------------------------------------
// prep_misc: WfG = W_seq^T in A-fragment order (unit (pt8,kt) at
// (pt8*16+kt)*512: p = pt8*32+(lane&31), k(d) = kt*16+(lane>>5)*8+e);
// GRU weight transposes.
// ---------------------------------------------------------------------------
__global__ __launch_bounds__(256) void prep_misc(
    const float* __restrict__ Wseq, const float* __restrict__ Wih,
    const float* __restrict__ Whh, u16* __restrict__ WfG,
    float* __restrict__ WT, float* __restrict__ UT) {
  const int bid = blockIdx.x, t = threadIdx.x;
  if (bid < 32) {
    const int unit = bid * 4 + (t >> 6);
    const int lane = t & 63, l31 = lane & 31, koct = lane >> 5;
    const int pt8 = unit >> 4, kt = unit & 15;
    u16x8 o;
#pragma unroll
    for (int e = 0; e < 8; ++e)
      o[e] = bf16_rne(
          Wseq[(long)(kt * 16 + koct * 8 + e) * 256 + pt8 * 32 + l31]);
    *(u16x8*)(WfG + (long)unit * 512 + lane * 8) = o;
  } else {
    const int g = bid - 32;  // 0..767
    WT[(long)t * 768 + g] = Wih[(long)g * 256 + t];
    UT[(long)t * 768 + g] = Whh[(long)g * 256 + t];
  }
}

// ---------------------------------------------------------------------------
// hw_q: hw[b][q*64..] = (h[b] @ W_h)[q*64..], grid (4,B) for parallelism.
// ---------------------------------------------------------------------------
__global__ __launch_bounds__(256) void hw_q(const float* __restrict__ h,
                                            const float* __restrict__ Wh,
                                            float* __restrict__ hw) {
  const int q = blockIdx.x, b = blockIdx.y, t = threadIdx.x;
  __shared__ float sh[256];
  __shared__ float sP[4][64];
  sh[t] = h[b * 256 + t];
  __syncthreads();
  const int j4 = t & 63, dg = t >> 6;
  const int j = q * 64 + j4;
  float g = 0.f;
#pragma unroll 4
  for (int k = dg * 64; k < dg * 64 + 64; ++k)
    g = fmaf(sh[k], Wh[(long)k * 256 + j], g);
  sP[dg][j4] = g;
  __syncthreads();
  if (t < 64)
    hw[b * 256 + q * 64 + t] = (sP[0][t] + sP[1][t]) + (sP[2][t] + sP[3][t]);
}

// ---------------------------------------------------------------------------
// bigstep: per (b, 256-row chunk). Swapped-operand GEMM: A = Wf (p rows, LDS),
// B = seqF (n cols, global, coalesced frags). acc = SP^T: p in regs, n in
// lanes -> score reduce = 32 in-reg FMA + 1 shfl. Then exp/esum + vec partial.
// 1024 thr = 16 waves = 4 pg x 4 ng; per wave 64p x 64n, acc 2x2 frags.
// ---------------------------------------------------------------------------
__global__ __launch_bounds__(1024) void bigstep(
    const u16* __restrict__ seqF, const u16* __restrict__ WfG,
    const float* __restrict__ hwbuf, const float* __restrict__ vatt,
    const float* __restrict__ mask, float* __restrict__ wbuf,
    float* __restrict__ esum, float* __restrict__ part, int N, int NCH,
    int B) {
  __shared__ u16 sW[65536];  // 128 KB Wf frags (linear copy)
  __shared__ float sQ[256][5];
  __shared__ float se[256], shw[256], svv[256], sredE[4];

  const int t = threadIdx.x;
  const int lane = t & 63, w = t >> 6;
  const int l31 = lane & 31, koct = lane >> 5;
  const int pg = w >> 2, ng = w & 3;
  const int b = blockIdx.y, chunk = blockIdx.x;

  // stage Wf -> LDS (linear, coalesced, conflict-free)
  u16x8 wreg[8];
#pragma unroll
  for (int i = 0; i < 8; ++i)
    wreg[i] = *(const u16x8*)(WfG + (long)(i * 1024 + t) * 8);
  if (t < 256) {
    shw[t] = hwbuf[b * 256 + t];
    svv[t] = vatt[t];
  }

  const u16* bs = seqF + ((long)(b * NCH + chunk) << 16);
  // n-block t8 = 2*ng -> unit base 32*ng -> elem offset ng*16384
  const u16* bs0 = bs + (long)ng * 16384 + lane * 8;
  const u16* bs1 = bs0 + 8192;  // t8 = 2*ng+1 (+16 units)

  // 4-deep B prefetch ring (named regs; covers HBM/L2 latency)
  u16x8 s0a, s0b, s1a, s1b, s2a, s2b, s3a, s3b;
  s0a = *(const u16x8*)(bs0 + 0 * 512);
  s0b = *(const u16x8*)(bs1 + 0 * 512);
  s1a = *(const u16x8*)(bs0 + 1 * 512);
  s1b = *(const u16x8*)(bs1 + 1 * 512);
  s2a = *(const u16x8*)(bs0 + 2 * 512);
  s2b = *(const u16x8*)(bs1 + 2 * 512);
  s3a = *(const u16x8*)(bs0 + 3 * 512);
  s3b = *(const u16x8*)(bs1 + 3 * 512);

#pragma unroll
  for (int i = 0; i < 8; ++i) *(u16x8*)(&sW[(i * 1024 + t) * 8]) = wreg[i];
  __syncthreads();

  f32x16 acc00 = (f32x16)0.f, acc01 = (f32x16)0.f, acc10 = (f32x16)0.f,
         acc11 = (f32x16)0.f;
  // p-block pt8 = 2*pg -> elem offset pg*16384; pt8 = 2*pg+1 -> +8192
  const u16* wbase0 = &sW[pg * 16384 + lane * 8];
  const u16* wbase1 = wbase0 + 8192;

#define STEPK(Sa, Sb, kk)                                                     \
  {                                                                           \
    bf16x8 af0 = *(const bf16x8*)(wbase0 + (kk) * 512);                       \
    bf16x8 af1 = *(const bf16x8*)(wbase1 + (kk) * 512);                       \
    bf16x8 bf0 = *(bf16x8*)&Sa;                                               \
    bf16x8 bf1 = *(bf16x8*)&Sb;                                               \
    acc00 = __builtin_amdgcn_mfma_f32_32x32x16_bf16(af0, bf0, acc00, 0, 0, 0);\
    acc01 = __builtin_amdgcn_mfma_f32_32x32x16_bf16(af0, bf1, acc01, 0, 0, 0);\
    acc10 = __builtin_amdgcn_mfma_f32_32x32x16_bf16(af1, bf0, acc10, 0, 0, 0);\
    acc11 = __builtin_amdgcn_mfma_f32_32x32x16_bf16(af1, bf1, acc11, 0, 0, 0);\
  }
#define LOADK(Sa, Sb, kk)                   \
  {                                         \
    Sa = *(const u16x8*)(bs0 + (kk) * 512); \
    Sb = *(const u16x8*)(bs1 + (kk) * 512); \
  }

#pragma unroll 1
  for (int k4 = 0; k4 < 4; ++k4) {
    const int kt = k4 * 4;
    STEPK(s0a, s0b, kt + 0);
    if (k4 < 3) LOADK(s0a, s0b, kt + 4);
    STEPK(s1a, s1b, kt + 1);
    if (k4 < 3) LOADK(s1a, s1b, kt + 5);
    STEPK(s2a, s2b, kt + 2);
    if (k4 < 3) LOADK(s2a, s2b, kt + 6);
    STEPK(s3a, s3b, kt + 3);
    if (k4 < 3) LOADK(s3a, s3b, kt + 7);
  }
#undef STEPK
#undef LOADK

  // ---- scores: per lane, 2 cols (n0 = ng*64+l31, n1 = +32), p in regs ----
  float sc0 = 0.f, sc1 = 0.f;
  {
    auto accum = [&](const f32x16& A0, const f32x16& A1, int pbase) {
#pragma unroll
      for (int r = 0; r < 16; ++r) {
        const int pidx = pbase + (r & 3) + 8 * (r >> 2) + 4 * koct;
        const float pv = svv[pidx], ph = shw[pidx];
        sc0 = fmaf(pv, fast_tanh(A0[r] + ph), sc0);
        sc1 = fmaf(pv, fast_tanh(A1[r] + ph), sc1);
      }
    };
    accum(acc00, acc01, pg * 64);
    accum(acc10, acc11, pg * 64 + 32);
  }
  sc0 += __shfl_xor(sc0, 32, 64);
  sc1 += __shfl_xor(sc1, 32, 64);
  if (koct == 0) {
    sQ[ng * 64 + l31][pg] = sc0;
    sQ[ng * 64 + 32 + l31][pg] = sc1;
  }
  __syncthreads();
  if (t < 256) {
    float s = (sQ[t][0] + sQ[t][1]) + (sQ[t][2] + sQ[t][3]);
    const long n = (long)b * N + chunk * 256 + t;
    float e = (mask[n] > 0.f) ? __expf(s) : 0.f;
    se[t] = e;
    wbuf[n] = e;
    float s4 = e;
#pragma unroll
    for (int off = 1; off < 64; off <<= 1) s4 += __shfl_xor(s4, off, 64);
    if ((t & 63) == 0) sredE[t >> 6] = s4;
  }
  __syncthreads();
  if (t == 0)
    esum[b * NCH + chunk] = (sredE[0] + sredE[1]) + (sredE[2] + sredE[3]);

  // ---- vec partial: wave w = kt; coalesced frag loads (L1/L2-hot) ----
  const int kt = w;
  float vd0 = 0, vd1 = 0, vd2 = 0, vd3 = 0, vd4 = 0, vd5 = 0, vd6 = 0,
        vd7 = 0;
  const u16* vb = bs + ((long)kt * 64 + lane) * 8;
#pragma unroll
  for (int t8 = 0; t8 < 8; ++t8) {
    u16x8 q = *(const u16x8*)(vb + (long)t8 * 8192);
    const float wv = se[t8 * 32 + l31];
    vd0 = fmaf(wv, bf16f((u16)q[0]), vd0);
    vd1 = fmaf(wv, bf16f((u16)q[1]), vd1);
    vd2 = fmaf(wv, bf16f((u16)q[2]), vd2);
    vd3 = fmaf(wv, bf16f((u16)q[3]), vd3);
    vd4 = fmaf(wv, bf16f((u16)q[4]), vd4);
    vd5 = fmaf(wv, bf16f((u16)q[5]), vd5);
    vd6 = fmaf(wv, bf16f((u16)q[6]), vd6);
    vd7 = fmaf(wv, bf16f((u16)q[7]), vd7);
  }
#pragma unroll
  for (int off = 1; off < 32; off <<= 1) {
    vd0 += __shfl_xor(vd0, off, 64);
    vd1 += __shfl_xor(vd1, off, 64);
    vd2 += __shfl_xor(vd2, off, 64);
    vd3 += __shfl_xor(vd3, off, 64);
    vd4 += __shfl_xor(vd4, off, 64);
    vd5 += __shfl_xor(vd5, off, 64);
    vd6 += __shfl_xor(vd6, off, 64);
    vd7 += __shfl_xor(vd7, off, 64);
  }
  if (l31 == 0) {
    float4 o0 = {vd0, vd1, vd2, vd3};
    float4 o1 = {vd4, vd5, vd6, vd7};
    float* pp = part + (long)(chunk * B + b) * 256 + kt * 16 + koct * 8;
    *(float4*)pp = o0;
    *(float4*)(pp + 4) = o1;
  }
}

// ---------------------------------------------------------------------------
// finalize: S-reduce (8 partials), vec normalize, GRU (j-split over q),
// w-normalize + out write. grid (4, B).
// ---------------------------------------------------------------------------
__global__ __launch_bounds__(256) void finalize_gru(
    const float* __restrict__ part, const float* __restrict__ esumP, int ecnt,
    const float* __restrict__ hprev, const float* __restrict__ WT,
    const float* __restrict__ UT, const float* __restrict__ bih,
    const float* __restrict__ bhh, const float* __restrict__ wbuf,
    float* __restrict__ out, float* __restrict__ hnew, int N, int T, int step,
    int NP, int B) {
  const int q = blockIdx.x, b = blockIdx.y, t = threadIdx.x;
  __shared__ float sv[256], sh[256], sP[6][4][64];
  float S = 0.f;
  for (int i = 0; i < ecnt; ++i) S += esumP[b * ecnt + i];
  const float inv = 1.f / S;
  float a = 0.f;
  for (int cc = 0; cc < NP; ++cc) a += part[((long)cc * B + b) * 256 + t];
  sv[t] = a * inv;
  sh[t] = hprev[b * 256 + t];
  __syncthreads();
  const int j4 = t & 63, dg = t >> 6;
  const int j = q * 64 + j4;
  float g0 = 0, g1 = 0, g2 = 0, g3 = 0, g4 = 0, g5 = 0;
#pragma unroll 4
  for (int d = dg * 64; d < dg * 64 + 64; ++d) {
    const float vd = sv[d], hd = sh[d];
    const float* wr_ = WT + (long)d * 768 + j;
    const float* ur_ = UT + (long)d * 768 + j;
    g0 = fmaf(vd, wr_[0], g0);
    g1 = fmaf(vd, wr_[256], g1);
    g2 = fmaf(vd, wr_[512], g2);
    g3 = fmaf(hd, ur_[0], g3);
    g4 = fmaf(hd, ur_[256], g4);
    g5 = fmaf(hd, ur_[512], g5);
  }
  sP[0][dg][j4] = g0;
  sP[1][dg][j4] = g1;
  sP[2][dg][j4] = g2;
  sP[3][dg][j4] = g3;
  sP[4][dg][j4] = g4;
  sP[5][dg][j4] = g5;
  __syncthreads();
  if (t < 64) {
    const int jj = q * 64 + t;
    float xr = bih[jj], xz = bih[256 + jj], xn = bih[512 + jj];
    float hr = bhh[jj], hz = bhh[256 + jj], hn = bhh[512 + jj];
#pragma unroll
    for (int dgg = 0; dgg < 4; ++dgg) {
      xr += sP[0][dgg][t];
      xz += sP[1][dgg][t];
      xn += sP[2][dgg][t];
      hr += sP[3][dgg][t];
      hz += sP[4][dgg][t];
      hn += sP[5][dgg][t];
    }
    float rr = sigmoidf_(xr + hr);
    float zz = sigmoidf_(xz + hz);
    float nn = fast_tanh(xn + rr * hn);
    hnew[b * 256 + jj] = (1.f - zz) * nn + zz * sh[jj];
  }
  const long ob = ((long)b * T + step) * N;
  const int nq = N >> 2;
  for (int i = 0; i * 256 < nq; ++i) {
    const int n = q * nq + i * 256 + t;
    out[ob + n] = wbuf[(long)b * N + n] * inv;
  }
}

// ---------------------------------------------------------------------------
extern "C" void kernel_launch(void* const* d_in, const int* in_sizes, int n_in,
                              void* d_out, int out_size, void* d_ws,
                              size_t ws_size, hipStream_t stream) {
  (void)n_in;
  (void)ws_size;
  const float* seq = (const float*)d_in[0];
  const float* hidden = (const float*)d_in[1];
  const float* mask = (const float*)d_in[2];
  const float* Wseq = (const float*)d_in[4];
  const float* Wh = (const float*)d_in[5];
  const float* vatt = (const float*)d_in[6];
  const float* Wih = (const float*)d_in[7];
  const float* Whh = (const float*)d_in[8];
  const float* bih = (const float*)d_in[9];
  const float* bhh = (const float*)d_in[10];
  float* out = (float*)d_out;

  const int P = in_sizes[6];
  const int H = in_sizes[5] / P;
  const int B = in_sizes[1] / H;
  const int N = in_sizes[2] / B;
  const int T = out_size / (B * N);
  const long M = (long)B * N;
  const int NCH = N / 256;

  char* p = (char*)d_ws;
  auto alloc = [&](size_t bytes) {
    char* r = p;
    p += (bytes + 255) & ~(size_t)255;
    return r;
  };
  u16* seqF = (u16*)alloc((size_t)M * 256 * 2);
  u16* WfG = (u16*)alloc((size_t)256 * 256 * 2);
  float* WT = (float*)alloc((size_t)256 * 768 * 4);
  float* UT = (float*)alloc((size_t)256 * 768 * 4);
  float* wbuf = (float*)alloc((size_t)B * N * 4);
  float* hwbuf = (float*)alloc((size_t)B * 256 * 4);
  float* hA = (float*)alloc((size_t)B * 256 * 4);
  float* hB = (float*)alloc((size_t)B * 256 * 4);
  float* part = (float*)alloc((size_t)NCH * B * 256 * 4);
  float* esum = (float*)alloc((size_t)B * NCH * 4);
  float* hbuf[2] = {hA, hB};

  prep_seqF<<<dim3(NCH, B), dim3(1024), 0, stream>>>(seq, seqF, N, NCH);
  prep_misc<<<dim3(800), dim3(256), 0, stream>>>(Wseq, Wih, Whh, WfG, WT, UT);

  for (int t = 0; t < T; ++t) {
    const float* hcur = (t == 0) ? hidden : hbuf[(t - 1) & 1];
    hw_q<<<dim3(4, B), dim3(256), 0, stream>>>(hcur, Wh, hwbuf);
    bigstep<<<dim3(NCH, B), dim3(1024), 0, stream>>>(
        seqF, WfG, hwbuf, vatt, mask, wbuf, esum, part, N, NCH, B);
    finalize_gru<<<dim3(4, B), dim3(256), 0, stream>>>(
        part, esum, NCH, hcur, WT, UT, bih, bhh, wbuf, out, hbuf[t & 1], N, T,
        t, NCH, B);
  }
}

// Round 8
// 161.525 us; speedup vs baseline: 1.8828x; 1.0013x over previous
//
#include <hip/hip_runtime.h>
#include <cstdint>

using u16 = unsigned short;
using u32 = unsigned int;
typedef __attribute__((ext_vector_type(8))) short bf16x8;
typedef __attribute__((ext_vector_type(8))) u16 u16x8;
typedef __attribute__((ext_vector_type(16))) float f32x16;
typedef __attribute__((ext_vector_type(4))) u16 u16x4;
typedef __attribute__((ext_vector_type(4))) u32 u32x4;

#define DEV static __device__ __forceinline__

DEV u16 bf16_rne(float x) {
  u32 u = __float_as_uint(x);
  u32 r = (u + 0x7FFFu + ((u >> 16) & 1u)) >> 16;
  return (u16)r;
}
DEV float bf16f(u16 h) { return __uint_as_float(((u32)h) << 16); }

DEV u32 cvt_pk_bf16(float lo, float hi) {
  u32 d;
  asm("v_cvt_pk_bf16_f32 %0, %1, %2" : "=v"(d) : "v"(lo), "v"(hi));
  return d;
}

DEV float fast_tanh(float x) {
  float e = __expf(2.0f * x);
  return 1.0f - 2.0f / (e + 1.0f);
}
DEV float sigmoidf_(float x) { return 1.0f / (1.0f + __expf(-x)); }

// ---------------------------------------------------------------------------
// prep_w: bid<32: WfG = W_seq^T in A-fragment order (unit (pt8*16+kt)*512
// elems: p = pt8*32+(lane&31), d = kt*16+(lane>>5)*8+e).
// bid>=32: GRU weight transposes, lanes = g (coalesced 256B stores; read
// gather amortized by d-loop via L1).
// ---------------------------------------------------------------------------
__global__ __launch_bounds__(256) void prep_w(const float* __restrict__ Wseq,
                                              const float* __restrict__ Wih,
                                              const float* __restrict__ Whh,
                                              u16* __restrict__ WfG,
                                              float* __restrict__ WT,
                                              float* __restrict__ UT) {
  const int bid = blockIdx.x, t = threadIdx.x;
  if (bid < 32) {
    const int unit = bid * 4 + (t >> 6);
    const int lane = t & 63, l31 = lane & 31, koct = lane >> 5;
    const int pt8 = unit >> 4, kt = unit & 15;
    u16x8 o;
#pragma unroll
    for (int e = 0; e < 8; ++e)
      o[e] = bf16_rne(
          Wseq[(long)(kt * 16 + koct * 8 + e) * 256 + pt8 * 32 + l31]);
    *(u16x8*)(WfG + (long)unit * 512 + lane * 8) = o;
  } else {
    const int gid = bid - 32;  // 0..23
    const float* src = (gid >= 12) ? Whh : Wih;
    float* dst = (gid >= 12) ? UT : WT;
    const int g = (gid % 12) * 64 + (t & 63);
    const int dq = t >> 6;
#pragma unroll 4
    for (int d = dq * 64; d < dq * 64 + 64; ++d)
      dst[(long)d * 768 + g] = src[(long)g * 256 + d];
  }
}

// ---------------------------------------------------------------------------
// bigstep<STEP0>: per (b, chunk-pair) block, 1024 thr = 16 waves (4 pg x 4 ng).
// seq frags in LDS (128 KB); W frags streamed from L2-global as A-operand.
// STEP0: f32 read -> cvt -> swizzled LDS transpose -> seqF writeout -> GEMM.
// STEP1: LDS fill via global_load_lds (linear frag copy) -> GEMM.
// Epilogue: score = v.tanh(acc+hw) (p in regs, n in lanes -> 1 shfl), max-free
// exp, block esum, vec partials. hw = h@W_h computed in-block (overlaps fill).
// ---------------------------------------------------------------------------
template <int STEP0>
__global__ __launch_bounds__(1024) void bigstep(
    const float* __restrict__ seq, u16* __restrict__ seqF,
    const u16* __restrict__ WfG, const float* __restrict__ hprev,
    const float* __restrict__ Wh, const float* __restrict__ vatt,
    const float* __restrict__ mask, float* __restrict__ wbuf,
    float* __restrict__ esum, float* __restrict__ part, int N, int NCH,
    int B) {
  __shared__ u16 sR[65536];  // 128 KB seq-fragment tile
  __shared__ float sQ[256][5];
  __shared__ float se[256], shw[256], svv[256], sredE[4];
  __shared__ float sHW[4][256];

  const int t = threadIdx.x, lane = t & 63, w = t >> 6;
  const int l31 = lane & 31, koct = lane >> 5;
  const int pg = w >> 2, ng = w & 3;
  const int b = blockIdx.y, cpair = blockIdx.x;
  char* sRb = (char*)sR;

  auto fillChunk = [&](int chunk) {
    if constexpr (STEP0) {
      const float* src = seq + ((long)b * N + chunk * 256) * 256;
#pragma unroll
      for (int i = 0; i < 8; ++i) {
        const int idx = i * 8192 + t * 8;
        float4 x = *(const float4*)(src + idx);
        float4 y = *(const float4*)(src + idx + 4);
        u32x4 o;
        o[0] = cvt_pk_bf16(x.x, x.y);
        o[1] = cvt_pk_bf16(x.z, x.w);
        o[2] = cvt_pk_bf16(y.x, y.y);
        o[3] = cvt_pk_bf16(y.z, y.w);
        const int row = idx >> 8, colb = (idx & 255) * 2;
        *(u32x4*)(sRb + row * 512 + (colb ^ ((row & 31) << 4))) = o;
      }
    } else {
      const u16* src = seqF + ((long)(b * NCH + chunk) << 16);
#pragma unroll
      for (int i = 0; i < 8; ++i) {
        const u16* g = src + ((long)(i * 1024 + t)) * 8;
        char* l = sRb + ((size_t)(i * 1024 + (t & ~63)) * 16);
        __builtin_amdgcn_global_load_lds(
            (const __attribute__((address_space(1))) u32*)g,
            (__attribute__((address_space(3))) u32*)l, 16, 0, 0);
      }
    }
  };

  auto writeoutChunk = [&](int chunk) {  // STEP0 only: sR -> seqF frags
    u16* dst = seqF + ((long)(b * NCH + chunk) << 16);
#pragma unroll
    for (int i = 0; i < 8; ++i) {
      const int u = i * 1024 + t;
      const int ln = u & 63, kt = (u >> 6) & 15, t8 = u >> 10;
      const int row = t8 * 32 + (ln & 31);
      const int colb = (kt * 16 + (ln >> 5) * 8) * 2;
      u16x8 v = *(const u16x8*)(sRb + row * 512 + (colb ^ ((row & 31) << 4)));
      *(u16x8*)(dst + (long)u * 8) = v;
    }
  };

  auto gemmChunk = [&](f32x16& a00, f32x16& a01, f32x16& a10, f32x16& a11) {
    const u16* wa0 = WfG + (long)(pg * 32) * 512 + lane * 8;
    const u16* wa1 = wa0 + 16 * 512;
    const char* p0;
    const char* p1;
    int sw0 = 0, sw1 = 0, cb = 0;
    if constexpr (STEP0) {
      const int row0 = ng * 64 + l31, row1 = row0 + 32;
      p0 = sRb + row0 * 512;
      p1 = sRb + row1 * 512;
      sw0 = (row0 & 31) << 4;
      sw1 = (row1 & 31) << 4;
      cb = koct * 16;
    } else {
      p0 = sRb + (size_t)(ng * 32768) + lane * 16;
      p1 = p0 + 16384;
    }
#pragma unroll 4
    for (int kt = 0; kt < 16; ++kt) {
      bf16x8 af0 = *(const bf16x8*)(wa0 + kt * 512);
      bf16x8 af1 = *(const bf16x8*)(wa1 + kt * 512);
      bf16x8 bf0, bf1;
      if constexpr (STEP0) {
        bf0 = *(const bf16x8*)(p0 + ((kt * 32 + cb) ^ sw0));
        bf1 = *(const bf16x8*)(p1 + ((kt * 32 + cb) ^ sw1));
      } else {
        bf0 = *(const bf16x8*)(p0 + kt * 1024);
        bf1 = *(const bf16x8*)(p1 + kt * 1024);
      }
      a00 = __builtin_amdgcn_mfma_f32_32x32x16_bf16(af0, bf0, a00, 0, 0, 0);
      a01 = __builtin_amdgcn_mfma_f32_32x32x16_bf16(af0, bf1, a01, 0, 0, 0);
      a10 = __builtin_amdgcn_mfma_f32_32x32x16_bf16(af1, bf0, a10, 0, 0, 0);
      a11 = __builtin_amdgcn_mfma_f32_32x32x16_bf16(af1, bf1, a11, 0, 0, 0);
    }
  };

  auto epiChunk = [&](int chunk, const f32x16& a00, const f32x16& a01,
                      const f32x16& a10, const f32x16& a11) {
    float sc0 = 0.f, sc1 = 0.f;
#pragma unroll
    for (int r = 0; r < 16; ++r) {
      const int pidx = pg * 64 + (r & 3) + 8 * (r >> 2) + 4 * koct;
      const float pv = svv[pidx], ph = shw[pidx];
      sc0 = fmaf(pv, fast_tanh(a00[r] + ph), sc0);
      sc1 = fmaf(pv, fast_tanh(a01[r] + ph), sc1);
    }
#pragma unroll
    for (int r = 0; r < 16; ++r) {
      const int pidx = pg * 64 + 32 + (r & 3) + 8 * (r >> 2) + 4 * koct;
      const float pv = svv[pidx], ph = shw[pidx];
      sc0 = fmaf(pv, fast_tanh(a10[r] + ph), sc0);
      sc1 = fmaf(pv, fast_tanh(a11[r] + ph), sc1);
    }
    sc0 += __shfl_xor(sc0, 32, 64);
    sc1 += __shfl_xor(sc1, 32, 64);
    if (koct == 0) {
      sQ[ng * 64 + l31][pg] = sc0;
      sQ[ng * 64 + 32 + l31][pg] = sc1;
    }
    __syncthreads();
    if (t < 256) {
      float s = (sQ[t][0] + sQ[t][1]) + (sQ[t][2] + sQ[t][3]);
      const long n = (long)b * N + chunk * 256 + t;
      float e = (mask[n] > 0.f) ? __expf(s) : 0.f;
      se[t] = e;
      wbuf[n] = e;
      float s4 = e;
#pragma unroll
      for (int off = 1; off < 64; off <<= 1) s4 += __shfl_xor(s4, off, 64);
      if ((t & 63) == 0) sredE[t >> 6] = s4;
    }
    __syncthreads();
    if (t == 0)
      esum[b * NCH + chunk] = (sredE[0] + sredE[1]) + (sredE[2] + sredE[3]);
    // vec partial: wave w = kt; frag loads from global seqF (L2-hot)
    const u16* bs = seqF + ((long)(b * NCH + chunk) << 16);
    const int kt = w;
    float vd0 = 0, vd1 = 0, vd2 = 0, vd3 = 0, vd4 = 0, vd5 = 0, vd6 = 0,
          vd7 = 0;
    const u16* vb = bs + ((long)kt * 64 + lane) * 8;
#pragma unroll
    for (int t8 = 0; t8 < 8; ++t8) {
      u16x8 q = *(const u16x8*)(vb + (long)t8 * 8192);
      const float wv = se[t8 * 32 + l31];
      vd0 = fmaf(wv, bf16f((u16)q[0]), vd0);
      vd1 = fmaf(wv, bf16f((u16)q[1]), vd1);
      vd2 = fmaf(wv, bf16f((u16)q[2]), vd2);
      vd3 = fmaf(wv, bf16f((u16)q[3]), vd3);
      vd4 = fmaf(wv, bf16f((u16)q[4]), vd4);
      vd5 = fmaf(wv, bf16f((u16)q[5]), vd5);
      vd6 = fmaf(wv, bf16f((u16)q[6]), vd6);
      vd7 = fmaf(wv, bf16f((u16)q[7]), vd7);
    }
#pragma unroll
    for (int off = 1; off < 32; off <<= 1) {
      vd0 += __shfl_xor(vd0, off, 64);
      vd1 += __shfl_xor(vd1, off, 64);
      vd2 += __shfl_xor(vd2, off, 64);
      vd3 += __shfl_xor(vd3, off, 64);
      vd4 += __shfl_xor(vd4, off, 64);
      vd5 += __shfl_xor(vd5, off, 64);
      vd6 += __shfl_xor(vd6, off, 64);
      vd7 += __shfl_xor(vd7, off, 64);
    }
    if (l31 == 0) {
      float4 o0 = {vd0, vd1, vd2, vd3};
      float4 o1 = {vd4, vd5, vd6, vd7};
      float* pp = part + (long)(chunk * B + b) * 256 + kt * 16 + koct * 8;
      *(float4*)pp = o0;
      *(float4*)(pp + 4) = o1;
    }
  };

  // ===== main flow: chunk pair =====
  const int c0 = cpair * 2, c1 = c0 + 1;
  fillChunk(c0);
  {  // hw = h @ W_h (overlaps fill latency)
    const int p_ = t & 255, kq = t >> 8;
    const float* hp = hprev + b * 256 + kq * 64;
    const float* whp = Wh + (long)kq * 64 * 256 + p_;
    float hacc = 0.f;
#pragma unroll 8
    for (int k = 0; k < 64; ++k) hacc = fmaf(hp[k], whp[(long)k * 256], hacc);
    sHW[kq][p_] = hacc;
    if (t < 256) svv[t] = vatt[t];
  }
  __syncthreads();  // fill(c0) + sHW ready
  if (t < 256) shw[t] = (sHW[0][t] + sHW[1][t]) + (sHW[2][t] + sHW[3][t]);
  if constexpr (STEP0) writeoutChunk(c0);
  f32x16 a00 = (f32x16)0.f, a01 = (f32x16)0.f, a10 = (f32x16)0.f,
         a11 = (f32x16)0.f;
  gemmChunk(a00, a01, a10, a11);
  __syncthreads();  // all waves done reading sR(c0); shw guaranteed ready
  fillChunk(c1);    // hides under chunk-0 epilogue
  epiChunk(c0, a00, a01, a10, a11);
  if constexpr (STEP0) writeoutChunk(c1);  // sR(c1) ready (epi barriers)
  f32x16 b00 = (f32x16)0.f, b01 = (f32x16)0.f, b10 = (f32x16)0.f,
         b11 = (f32x16)0.f;
  gemmChunk(b00, b01, b10, b11);
  epiChunk(c1, b00, b01, b10, b11);
}

// ---------------------------------------------------------------------------
// finalize: S-reduce (NCH partials), vec normalize, GRU (j-split over q),
// w-normalize + out write. grid (4, B).
// ---------------------------------------------------------------------------
__global__ __launch_bounds__(256) void finalize_gru(
    const float* __restrict__ part, const float* __restrict__ esumP, int ecnt,
    const float* __restrict__ hprev, const float* __restrict__ WT,
    const float* __restrict__ UT, const float* __restrict__ bih,
    const float* __restrict__ bhh, const float* __restrict__ wbuf,
    float* __restrict__ out, float* __restrict__ hnew, int N, int T, int step,
    int NP, int B) {
  const int q = blockIdx.x, b = blockIdx.y, t = threadIdx.x;
  __shared__ float sv[256], sh[256], sP[6][4][64];
  float S = 0.f;
  for (int i = 0; i < ecnt; ++i) S += esumP[b * ecnt + i];
  const float inv = 1.f / S;
  float a = 0.f;
  for (int cc = 0; cc < NP; ++cc) a += part[((long)cc * B + b) * 256 + t];
  sv[t] = a * inv;
  sh[t] = hprev[b * 256 + t];
  __syncthreads();
  const int j4 = t & 63, dg = t >> 6;
  const int j = q * 64 + j4;
  float g0 = 0, g1 = 0, g2 = 0, g3 = 0, g4 = 0, g5 = 0;
#pragma unroll 4
  for (int d = dg * 64; d < dg * 64 + 64; ++d) {
    const float vd = sv[d], hd = sh[d];
    const float* wr_ = WT + (long)d * 768 + j;
    const float* ur_ = UT + (long)d * 768 + j;
    g0 = fmaf(vd, wr_[0], g0);
    g1 = fmaf(vd, wr_[256], g1);
    g2 = fmaf(vd, wr_[512], g2);
    g3 = fmaf(hd, ur_[0], g3);
    g4 = fmaf(hd, ur_[256], g4);
    g5 = fmaf(hd, ur_[512], g5);
  }
  sP[0][dg][j4] = g0;
  sP[1][dg][j4] = g1;
  sP[2][dg][j4] = g2;
  sP[3][dg][j4] = g3;
  sP[4][dg][j4] = g4;
  sP[5][dg][j4] = g5;
  __syncthreads();
  if (t < 64) {
    const int jj = q * 64 + t;
    float xr = bih[jj], xz = bih[256 + jj], xn = bih[512 + jj];
    float hr = bhh[jj], hz = bhh[256 + jj], hn = bhh[512 + jj];
#pragma unroll
    for (int dgg = 0; dgg < 4; ++dgg) {
      xr += sP[0][dgg][t];
      xz += sP[1][dgg][t];
      xn += sP[2][dgg][t];
      hr += sP[3][dgg][t];
      hz += sP[4][dgg][t];
      hn += sP[5][dgg][t];
    }
    float rr = sigmoidf_(xr + hr);
    float zz = sigmoidf_(xz + hz);
    float nn = fast_tanh(xn + rr * hn);
    hnew[b * 256 + jj] = (1.f - zz) * nn + zz * sh[jj];
  }
  const long ob = ((long)b * T + step) * N;
  const int nq = N >> 2;
  for (int i = 0; i * 256 < nq; ++i) {
    const int n = q * nq + i * 256 + t;
    out[ob + n] = wbuf[(long)b * N + n] * inv;
  }
}

// ---------------------------------------------------------------------------
extern "C" void kernel_launch(void* const* d_in, const int* in_sizes, int n_in,
                              void* d_out, int out_size, void* d_ws,
                              size_t ws_size, hipStream_t stream) {
  (void)n_in;
  (void)ws_size;
  const float* seq = (const float*)d_in[0];
  const float* hidden = (const float*)d_in[1];
  const float* mask = (const float*)d_in[2];
  const float* Wseq = (const float*)d_in[4];
  const float* Wh = (const float*)d_in[5];
  const float* vatt = (const float*)d_in[6];
  const float* Wih = (const float*)d_in[7];
  const float* Whh = (const float*)d_in[8];
  const float* bih = (const float*)d_in[9];
  const float* bhh = (const float*)d_in[10];
  float* out = (float*)d_out;

  const int P = in_sizes[6];
  const int H = in_sizes[5] / P;
  const int B = in_sizes[1] / H;
  const int N = in_sizes[2] / B;
  const int T = out_size / (B * N);
  const long M = (long)B * N;
  const int NCH = N / 256;

  char* p = (char*)d_ws;
  auto alloc = [&](size_t bytes) {
    char* r = p;
    p += (bytes + 255) & ~(size_t)255;
    return r;
  };
  u16* seqF = (u16*)alloc((size_t)M * 256 * 2);
  u16* WfG = (u16*)alloc((size_t)256 * 256 * 2);
  float* WT = (float*)alloc((size_t)256 * 768 * 4);
  float* UT = (float*)alloc((size_t)256 * 768 * 4);
  float* wbuf = (float*)alloc((size_t)B * N * 4);
  float* hA = (float*)alloc((size_t)B * 256 * 4);
  float* hB = (float*)alloc((size_t)B * 256 * 4);
  float* part = (float*)alloc((size_t)NCH * B * 256 * 4);
  float* esum = (float*)alloc((size_t)B * NCH * 4);
  float* hbuf[2] = {hA, hB};

  prep_w<<<dim3(56), dim3(256), 0, stream>>>(Wseq, Wih, Whh, WfG, WT, UT);

  for (int t = 0; t < T; ++t) {
    const float* hcur = (t == 0) ? hidden : hbuf[(t - 1) & 1];
    if (t == 0) {
      bigstep<1><<<dim3(NCH / 2, B), dim3(1024), 0, stream>>>(
          seq, seqF, WfG, hcur, Wh, vatt, mask, wbuf, esum, part, N, NCH, B);
    } else {
      bigstep<0><<<dim3(NCH / 2, B), dim3(1024), 0, stream>>>(
          seq, seqF, WfG, hcur, Wh, vatt, mask, wbuf, esum, part, N, NCH, B);
    }
    finalize_gru<<<dim3(4, B), dim3(256), 0, stream>>>(
        part, esum, NCH, hcur, WT, UT, bih, bhh, wbuf, out, hbuf[t & 1], N, T,
        t, NCH, B);
  }
}